// Round 10
// baseline (79.865 us; speedup 1.0000x reference)
//
#include <hip/hip_runtime.h>
#include <math.h>

// NoisyEmbedding: argmax_j( cos_sim(w[ids[i]], w[j]) + 20*gumbel[i][j] ) -> gather w[argmax]
//
// sims span <= 2 => only j with gumbel g within 0.1 of the ROW max can win
// (20*0.1 = 2). g = -log(-log u) monotone in u => all max/threshold work in
// the u-domain (no transcendentals in the stream). Two-level filter:
//   batch: keep survivors within 0.105 of their 2048-elem batch max
//   row:   re-filter to within 0.12 of the row max (~1.13 survive), exact
//          f32 rescore, argmax (score desc, idx asc) = jnp.argmax, gather.
//
// ONE kernel, ONE block per row (2048 blocks): row max + candidates are
// block-local => no second kernel, no workspace, no global atomics
// (round-5 coherence lesson). Unlike round 8's failed fusion: NO barriers
// in the scan (waves own contiguous quarter-rows, private LDS lists,
// within-wave LDS program order) and NO launch_bounds VGPR cap.
// Row bases are 4B-aligned only (V odd): first/last f32x4 of the row carry
// neighbor-row strays, masked to -1 (edge batches only).

constexpr int V  = 50257;
constexpr int D  = 768;
constexpr int BT = 2048;
constexpr int WCAP = 32;                 // per-wave candidate cap (E ~ 7.8)
constexpr int RCAP = 32;                 // row-filtered cap (E ~ 1.13)
constexpr float KPOW_B = 1.1107096f;     // expf(0.105)  batch-level
constexpr float KPOW_R = 1.1274969f;     // expf(0.12)   row-level
constexpr float TWO_OVER_EPS = 20.0f;

typedef float f32x4 __attribute__((ext_vector_type(4)));

__global__ __launch_bounds__(256) void k_all(
    const float* __restrict__ gum, const float* __restrict__ w,
    const int* __restrict__ ids, float* __restrict__ out) {
  __shared__ __align__(16) float q[D];   // ~4.6 KB LDS total
  __shared__ float clu[4][WCAP];
  __shared__ int   cli[4][WCAP];
  __shared__ int   s_wcnt[4];
  __shared__ float s_wmax[4], s_red[4];
  __shared__ float lu[RCAP], lsc[RCAP];
  __shared__ int   li[RCAP];
  __shared__ float s_ut, s_invq;
  __shared__ int   s_n, s_sel;

  int tid = threadIdx.x, r = blockIdx.x;
  int lane = tid & 63, wid = tid >> 6;
  int lo = r * V, hi = lo + V;           // this block's row, flat elements
  int f4lo = lo >> 2, f4hi = (hi - 1) >> 2;
  int nf4 = f4hi - f4lo + 1;             // 12564 or 12565
  int qt  = (nf4 + 3) >> 2;              // f32x4 per wave quarter

  // ---- prologue: stage q + per-wave norm partial + counters (no barrier) --
  int qid = ids[r];
  float qs = 0.f;
#pragma unroll
  for (int k = 0; k < 3; ++k) {
    float x = w[(size_t)qid * D + k * 256 + tid];
    q[k * 256 + tid] = x;
    qs += x * x;
  }
#pragma unroll
  for (int off = 32; off > 0; off >>= 1) qs += __shfl_down(qs, off, 64);
  if (lane == 0) { s_red[wid] = qs; s_wcnt[wid] = 0; }  // before any push:
  if (tid == 0) s_n = 0;                 // within-wave LDS ops are in order

  // ---- scan: wave owns f4 span [wbeg, wend); 7 batches of 512 f32x4 ------
  const f32x4* g4 = reinterpret_cast<const f32x4*>(gum);
  int wbeg = f4lo + wid * qt;
  int wend = f4lo + nf4; { int e2 = wbeg + qt; if (e2 < wend) wend = e2; }
  float rmax = -1.f;
  for (int b = 0; b < 7; ++b) {
    int base = wbeg + b * 512;
    f32x4 v[8];
#pragma unroll
    for (int k = 0; k < 8; ++k) {
      int fi = base + k * 64 + lane;
      v[k] = (fi < wend) ? __builtin_nontemporal_load(&g4[fi])
                         : (f32x4){-1.f, -1.f, -1.f, -1.f};
    }
    // element masks only where the row misaligns: first f4 (wave 0 batch 0)
    // and the f4hi vector (lands in wave 3 batch 6 for both nf4 values)
    if ((wid == 0 && b == 0) || (wid == 3 && b == 6)) {
#pragma unroll
      for (int k = 0; k < 8; ++k) {
        int e0 = (base + k * 64 + lane) << 2;
#pragma unroll
        for (int j = 0; j < 4; ++j)
          if (e0 + j < lo || e0 + j >= hi) v[k][j] = -1.f;
      }
    }
    float m = -1.f;
#pragma unroll
    for (int k = 0; k < 8; ++k)
#pragma unroll
      for (int j = 0; j < 4; ++j) m = fmaxf(m, v[k][j]);
#pragma unroll
    for (int off = 1; off < 64; off <<= 1)
      m = fmaxf(m, __shfl_xor(m, off, 64));
    rmax = fmaxf(rmax, m);
    // g >= g_batchmax - 0.105 <=> u >= u_batchmax^KPOW_B (u in (0,1]).
    // Empty batch: m = -1 -> NaN threshold -> all compares false.
    float thr = expf(KPOW_B * logf(m));
#pragma unroll
    for (int k = 0; k < 8; ++k)
#pragma unroll
      for (int j = 0; j < 4; ++j) {
        float uu = v[k][j];
        if (uu >= thr) {                 // ~1.1 per batch; masked never pass
          int p = atomicAdd(&s_wcnt[wid], 1);      // LDS atomic, own list
          if (p < WCAP) {
            cli[wid][p] = (((base + k * 64 + lane) << 2) + j) - lo;
            clu[wid][p] = uu;
          }
        }
      }
  }
  if (lane == 0) s_wmax[wid] = rmax;
  __syncthreads();                       // THE barrier: lists/maxima/q ready

  // ---- epilogue: row threshold, row-filter, rescore, argmax, gather ------
  if (tid == 0) {
    float rm = fmaxf(fmaxf(s_wmax[0], s_wmax[1]), fmaxf(s_wmax[2], s_wmax[3]));
    s_ut = expf(KPOW_R * logf(rm));      // g >= g_rowmax - 0.12 in u-domain
    s_invq = 1.f / fmaxf(sqrtf(s_red[0] + s_red[1] + s_red[2] + s_red[3]), 1e-12f);
  }
  __syncthreads();
  float ut = s_ut, invq = s_invq;

  if (tid < 4 * WCAP) {                  // row-filter the 4 wave lists
    int ww = tid >> 5, k = tid & (WCAP - 1);
    int m2 = s_wcnt[ww]; if (m2 > WCAP) m2 = WCAP;
    if (k < m2 && clu[ww][k] >= ut) {    // ~1.13 survivors per row
      int p = atomicAdd(&s_n, 1);        // LDS atomic
      if (p < RCAP) { li[p] = cli[ww][k]; lu[p] = clu[ww][k]; }
    }
  }
  __syncthreads();
  int n = s_n; if (n > RCAP) n = RCAP;

  for (int cI = wid; cI < n; cI += 4) {  // one wave per candidate
    int j = li[cI];
    const float4* p  = reinterpret_cast<const float4*>(w + (size_t)j * D);
    const float4* qp = reinterpret_cast<const float4*>(q);
    float dot = 0.f, n2 = 0.f;
#pragma unroll
    for (int k = 0; k < 3; ++k) {
      float4 a  = p[k * 64 + lane];
      float4 bq = qp[k * 64 + lane];
      dot += a.x * bq.x + a.y * bq.y + a.z * bq.z + a.w * bq.w;
      n2  += a.x * a.x  + a.y * a.y  + a.z * a.z  + a.w * a.w;
    }
#pragma unroll
    for (int off = 32; off > 0; off >>= 1) {
      dot += __shfl_down(dot, off, 64);
      n2  += __shfl_down(n2,  off, 64);
    }
    if (lane == 0) {
      float invj = 1.f / fmaxf(sqrtf(n2), 1e-12f);
      lsc[cI] = invq * invj * dot + TWO_OVER_EPS * (-logf(-logf(lu[cI])));
    }
  }
  __syncthreads();

  if (wid == 0) {                        // argmax: (score desc, idx asc)
    float bs = -INFINITY;
    int bj = 0x7fffffff;
    for (int cI = lane; cI < n; cI += 64) {
      float sv = lsc[cI];
      int j = li[cI];
      if (sv > bs || (sv == bs && j < bj)) { bs = sv; bj = j; }
    }
#pragma unroll
    for (int off = 32; off > 0; off >>= 1) {
      float os = __shfl_down(bs, off, 64);
      int   oj = __shfl_down(bj, off, 64);
      if (os > bs || (os == bs && oj < bj)) { bs = os; bj = oj; }
    }
    if (lane == 0) s_sel = bj;
  }
  __syncthreads();

  int sel = s_sel;
#pragma unroll
  for (int k = 0; k < 3; ++k)
    out[(size_t)r * D + k * 256 + tid] = w[(size_t)sel * D + k * 256 + tid];
}

extern "C" void kernel_launch(void* const* d_in, const int* in_sizes, int n_in,
                              void* d_out, int out_size, void* d_ws, size_t ws_size,
                              hipStream_t stream) {
  const int*   ids = (const int*)d_in[0];    // input_ids (B*T)
  const float* w   = (const float*)d_in[1];  // weight (V*D)
  const float* gum = (const float*)d_in[2];  // gumbel_u (BT*V)
  float* out = (float*)d_out;

  k_all<<<BT, 256, 0, stream>>>(gum, w, ids, out);   // no ws, no memset
}